// Round 5
// baseline (98.925 us; speedup 1.0000x reference)
//
#include <hip/hip_runtime.h>

// Causal attention, fp32 in/out, B=8 S=2048 D=64, NO 1/sqrt(d) scaling.
// R20 = R18 body + 32-row q-tiles (transaction HALVING, the only lever
// that has ever paid on this kernel):
//  - R19 post-mortem: occupancy 2x (2->4 blocks/CU) neutral AGAIN (90.77
//    -> 90.27us). With R17 that's two clean A/Bs: NOT latency-bound, NOT
//    issue-bound (VALU 23%, MFMA 7%). Work-conserving transaction bound.
//  - R20: each block owns 32 q-rows as TWO 16-row MFMA tiles sharing every
//    K-fragment load; waves keep disjoint 128-key chunks (kb/128 mod 4,
//    identical chunk grid as R18/R19). K+V L2 traffic 405 -> 203 MB.
//    MFMA/subtile 6->12 (total conserved), exp/f2bf/DPP conserved.
//  - Numerics bit-identical to R18/R19 (same chunk partition, same online
//    softmax order, same combine) -> absmax must stay exactly 0.03125.
//  - Safety: entered iterations have kb <= q0 (kb mult 128, q0 mult 32),
//    so every row sees >=1 unmasked key in its first chunk; m finite.
//  - A/B subtile pairing dropped (12 MFMA/subtile hides latency now);
//    VGPR ~160 -> 2-3 waves/SIMD, irrelevant per R17/R19. Spill tripwire:
//    WRITE_SIZE must stay ~4MB (R16 spills showed as +94MB HBM).
// Ledger: ~43us ws-poison fill + ~13us launch/misc fixed; attn floor ~6us
// (203MB @ 34.5TB/s).
// Fragment layouts (verified R2):
//   A[m][k]: m=lane&15, k=quad*8+j | B[k][n]: n=lane&15, k=quad*8+j
//   C/D:     col=lane&15, row=quad*4+reg
// Vf layout: chunk c(32 keys), dim-group nt: lane l holds
//   V[b][c*32+(l>>4)*8+j][nt*16+(l&15)], j=0..7 (16B, consecutive by lane).
// Kf layout: subtile S(16 keys), frag f: lane l holds 16B at
//   Kf + (b*128+S)*2048 + f*512 + l*8   (elements, 2B each)
//   f0/f1 = hi dims 0-31 / 32-63, f2/f3 = lo dims 0-31 / 32-63.

#define BATCH 8
#define SEQ 2048
#define DIM 64
#define NEL (BATCH * SEQ * DIM)

typedef __attribute__((ext_vector_type(8))) short short8;
typedef __attribute__((ext_vector_type(4))) float f32x4;

#define MFMA(a, b, c) __builtin_amdgcn_mfma_f32_16x16x32_bf16(a, b, c, 0, 0, 0)

__device__ __forceinline__ unsigned short f2bf(float x) {   // RNE
    unsigned u = __float_as_uint(x);
    unsigned r = u + 0x7fffu + ((u >> 16) & 1u);
    return (unsigned short)(r >> 16);
}
__device__ __forceinline__ float bf2f(unsigned short h) {
    return __uint_as_float(((unsigned)h) << 16);
}
__device__ __forceinline__ short8 ld8(const unsigned short* p) {
    return *(const short8*)p;
}
// truncation hi/lo split (R14-verified): hi = upper16(x); lo = trunc16(x-hi).
__device__ __forceinline__ void splitA(float4 a, float4 b, short8& h8, short8& l8) {
    float v[8] = {a.x, a.y, a.z, a.w, b.x, b.y, b.z, b.w};
#pragma unroll
    for (int i = 0; i < 8; ++i) {
        unsigned u  = __float_as_uint(v[i]);
        unsigned hu = u & 0xffff0000u;
        h8[i] = (short)(hu >> 16);
        float lf = v[i] - __uint_as_float(hu);
        l8[i] = (short)(__float_as_uint(lf) >> 16);
    }
}

__device__ __forceinline__ float dpp_max16(float x) {
    float o;
    o = __int_as_float(__builtin_amdgcn_update_dpp(0, __float_as_int(x), 0xB1, 0xF, 0xF, true));
    x = fmaxf(x, o);
    o = __int_as_float(__builtin_amdgcn_update_dpp(0, __float_as_int(x), 0x4E, 0xF, 0xF, true));
    x = fmaxf(x, o);
    o = __int_as_float(__builtin_amdgcn_update_dpp(0, __float_as_int(x), 0x141, 0xF, 0xF, true));
    x = fmaxf(x, o);
    o = __int_as_float(__builtin_amdgcn_update_dpp(0, __float_as_int(x), 0x140, 0xF, 0xF, true));
    return fmaxf(x, o);
}
__device__ __forceinline__ float dpp_sum16(float x) {
    float o;
    o = __int_as_float(__builtin_amdgcn_update_dpp(0, __float_as_int(x), 0xB1, 0xF, 0xF, true));
    x += o;
    o = __int_as_float(__builtin_amdgcn_update_dpp(0, __float_as_int(x), 0x4E, 0xF, 0xF, true));
    x += o;
    o = __int_as_float(__builtin_amdgcn_update_dpp(0, __float_as_int(x), 0x141, 0xF, 0xF, true));
    x += o;
    o = __int_as_float(__builtin_amdgcn_update_dpp(0, __float_as_int(x), 0x140, 0xF, 0xF, true));
    return x + o;
}

// ---- pre-pass: K fragment-major hi/lo (blk<512) + V fragment-major ----
__global__ __launch_bounds__(256) void prep(
    const float* __restrict__ K, const float* __restrict__ V,
    unsigned short* __restrict__ Kf, unsigned short* __restrict__ Vf)
{
    __shared__ unsigned short sT[64][72];   // [dim][key] for one 64-key tile
    const int blk = blockIdx.x;
    const int t = threadIdx.x;

    if (blk < 512) {
        // one thread = one (subtile, dim-half, lane) chunk: 8 fp32 -> hi8+lo8
        const int g  = blk * 256 + t;       // 0..131071
        const int l  = g & 63;
        const int h  = (g >> 6) & 1;
        const int Sg = g >> 7;              // b*128 + S, 0..1023
        const int b  = Sg >> 7;
        const int S  = Sg & 127;
        const int key = S * 16 + (l & 15);
        const float* src = K + ((size_t)(b * SEQ + key)) * DIM + h * 32 + (l >> 4) * 8;
        float4 a = *(const float4*)src;
        float4 c = *(const float4*)(src + 4);
        float v[8] = {a.x, a.y, a.z, a.w, c.x, c.y, c.z, c.w};
        short8 h8, l8;
#pragma unroll
        for (int i = 0; i < 8; ++i) {
            unsigned short hh = f2bf(v[i]);
            h8[i] = (short)hh;
            l8[i] = (short)f2bf(v[i] - bf2f(hh));
        }
        unsigned short* dst = Kf + (((size_t)Sg) << 11) + (h << 9) + l * 8;
        *(short8*)dst = h8;                  // frag f = h   (hi)
        *(short8*)(dst + 1024) = l8;         // frag f = 2+h (lo)
        return;
    }

    const int tile = blk - 512;             // 8 batches * 32 tiles of 64 keys
    const int b = tile >> 5;
    const int s0 = (tile & 31) * 64;
    const int srow = t >> 4;
    const int d4   = (t & 15) * 4;
#pragma unroll
    for (int i = 0; i < 4; ++i) {
        const int row = srow + i * 16;
        float4 v = *(const float4*)(V + ((size_t)(b * SEQ + s0 + row)) * DIM + d4);
        sT[d4 + 0][row] = f2bf(v.x);
        sT[d4 + 1][row] = f2bf(v.y);
        sT[d4 + 2][row] = f2bf(v.z);
        sT[d4 + 3][row] = f2bf(v.w);
    }
    __syncthreads();
#pragma unroll
    for (int i = 0; i < 2; ++i) {
        const int fid = t + i * 256;
        const int cc  = fid >> 8;
        const int nt  = (fid >> 6) & 3;
        const int l   = fid & 63;
        const int key = cc * 32 + (l >> 4) * 8;
        const int dim = nt * 16 + (l & 15);
        const int c   = (s0 >> 5) + cc;
        unsigned short* dst =
            Vf + ((((size_t)(b * 64 + c)) * 4 + nt) << 9) + l * 8;
        *(float4*)dst = *(const float4*)&sT[dim][key];
    }
}

// ---- main: 512 blocks x 256 threads (4 waves), 32 q-rows per block ----
__global__ __launch_bounds__(256) void attn_main(
    const float* __restrict__ Q,
    const unsigned short* __restrict__ Kf,
    const unsigned short* __restrict__ Vf, float* __restrict__ O)
{
    // per-wave union scratch: sP (ushort[32][136]) == sO (float[32][68]) = 8704B
    __shared__ __align__(16) char scratch[4][8704];
    __shared__ float sMl[4][32][2];

    const int bid  = blockIdx.x;
    // snake over grid halves: CU c gets tiles {tl, 63-tl} -> const work
    const int gph  = bid >> 8;              // 0/1
    const int idx  = bid & 255;
    const int b    = idx & (BATCH - 1);
    const int tl   = idx >> 3;              // 0..31
    const int qt   = gph ? (63 - tl) : tl;  // 0..63

    const int t    = threadIdx.x;
    const int w    = t >> 6;
    const int lane = t & 63;
    const int quad = lane >> 4;
    const int n16  = lane & 15;
    const int boff = b * SEQ;

    unsigned short* sPw = (unsigned short*)scratch[w];   // [32][136]
    float*          sOw = (float*)scratch[w];            // [32][68]

    // base of this batch's Kf region, plus this lane's 16B slot
    const unsigned short* KfL = Kf + (((size_t)(b * 128)) << 11) + lane * 8;

    const int q0 = qt * 32;
    const int q_max = q0 + 31;

    // ---- Q fragments, both 16-row tiles: inline hi/lo truncation split ----
    short8 qAh0, qAl0, qAh1, qAl1, qBh0, qBl0, qBh1, qBl1;
    {
        const float* qa = Q + ((size_t)(boff + q0 + n16)) * DIM + quad * 8;
        splitA(*(const float4*)(qa),      *(const float4*)(qa + 4),  qAh0, qAl0);
        splitA(*(const float4*)(qa + 32), *(const float4*)(qa + 36), qAh1, qAl1);
        const float* qb = qa + 16 * DIM;
        splitA(*(const float4*)(qb),      *(const float4*)(qb + 4),  qBh0, qBl0);
        splitA(*(const float4*)(qb + 32), *(const float4*)(qb + 36), qBh1, qBl1);
    }

    float m0 = -1e30f, m1 = -1e30f, m2 = -1e30f, m3 = -1e30f;
    float m4 = -1e30f, m5 = -1e30f, m6 = -1e30f, m7 = -1e30f;
    float l0 = 0.f, l1 = 0.f, l2 = 0.f, l3 = 0.f;
    float l4 = 0.f, l5 = 0.f, l6 = 0.f, l7 = 0.f;
    f32x4 oacc0[4], oacc1[4];
#pragma unroll
    for (int i = 0; i < 4; ++i) {
        oacc0[i] = (f32x4){0.f, 0.f, 0.f, 0.f};
        oacc1[i] = (f32x4){0.f, 0.f, 0.f, 0.f};
    }

    for (int kb = w * 128; kb <= q_max; kb += 512) {
        const int nsub = min(8, ((q_max - kb) >> 4) + 1);
        const int nchain = (nsub + 1) >> 1;
        f32x4 sacc0[8], sacc1[8];

        // ---- QK^T: per subtile 4 contiguous 1KB K loads feed 12 MFMAs ----
#pragma unroll
        for (int st = 0; st < 8; ++st) {
            if (st < nsub) {
                const unsigned short* p = KfL + (((size_t)((kb >> 4) + st)) << 11);
                short8 kh0 = ld8(p),        kh1 = ld8(p + 512);
                short8 kl0 = ld8(p + 1024), kl1 = ld8(p + 1536);
                f32x4 a = (f32x4){0.f, 0.f, 0.f, 0.f};
                a = MFMA(qAh0, kh0, a);
                a = MFMA(qAh1, kh1, a);
                a = MFMA(qAh0, kl0, a);
                a = MFMA(qAh1, kl1, a);
                a = MFMA(qAl0, kh0, a);
                a = MFMA(qAl1, kh1, a);
                sacc0[st] = a;
                f32x4 c = (f32x4){0.f, 0.f, 0.f, 0.f};
                c = MFMA(qBh0, kh0, c);
                c = MFMA(qBh1, kh1, c);
                c = MFMA(qBh0, kl0, c);
                c = MFMA(qBh1, kl1, c);
                c = MFMA(qBl0, kh0, c);
                c = MFMA(qBl1, kh1, c);
                sacc1[st] = c;
            } else {
                sacc0[st] = (f32x4){-1e30f, -1e30f, -1e30f, -1e30f};
                sacc1[st] = (f32x4){-1e30f, -1e30f, -1e30f, -1e30f};
            }
        }

        // ---- causal mask: chunk overlaps some query row ----
        if (kb + 127 > q0) {
#pragma unroll
            for (int st = 0; st < 8; ++st) {
                if (st < nsub) {
                    const int key = kb + st * 16 + n16;
#pragma unroll
                    for (int r = 0; r < 4; ++r) {
                        if (key > q0 + quad * 4 + r)      sacc0[st][r] = -1e30f;
                        if (key > q0 + 16 + quad * 4 + r) sacc1[st][r] = -1e30f;
                    }
                }
            }
        }

        // ---- online softmax over 128 keys x 32 rows (DPP reductions) ----
        float mt0 = sacc0[0][0], mt1 = sacc0[0][1], mt2 = sacc0[0][2], mt3 = sacc0[0][3];
        float mt4 = sacc1[0][0], mt5 = sacc1[0][1], mt6 = sacc1[0][2], mt7 = sacc1[0][3];
#pragma unroll
        for (int st = 1; st < 8; ++st) {
            mt0 = fmaxf(mt0, sacc0[st][0]);
            mt1 = fmaxf(mt1, sacc0[st][1]);
            mt2 = fmaxf(mt2, sacc0[st][2]);
            mt3 = fmaxf(mt3, sacc0[st][3]);
            mt4 = fmaxf(mt4, sacc1[st][0]);
            mt5 = fmaxf(mt5, sacc1[st][1]);
            mt6 = fmaxf(mt6, sacc1[st][2]);
            mt7 = fmaxf(mt7, sacc1[st][3]);
        }
        mt0 = dpp_max16(mt0); mt1 = dpp_max16(mt1);
        mt2 = dpp_max16(mt2); mt3 = dpp_max16(mt3);
        mt4 = dpp_max16(mt4); mt5 = dpp_max16(mt5);
        mt6 = dpp_max16(mt6); mt7 = dpp_max16(mt7);
        const float mn0 = fmaxf(m0, mt0), mn1 = fmaxf(m1, mt1);
        const float mn2 = fmaxf(m2, mt2), mn3 = fmaxf(m3, mt3);
        const float mn4 = fmaxf(m4, mt4), mn5 = fmaxf(m5, mt5);
        const float mn6 = fmaxf(m6, mt6), mn7 = fmaxf(m7, mt7);
        const float a0 = __expf(m0 - mn0), a1 = __expf(m1 - mn1);
        const float a2 = __expf(m2 - mn2), a3 = __expf(m3 - mn3);
        const float a4 = __expf(m4 - mn4), a5 = __expf(m5 - mn5);
        const float a6 = __expf(m6 - mn6), a7 = __expf(m7 - mn7);
        m0 = mn0; m1 = mn1; m2 = mn2; m3 = mn3;
        m4 = mn4; m5 = mn5; m6 = mn6; m7 = mn7;

        float ps0 = 0.f, ps1 = 0.f, ps2 = 0.f, ps3 = 0.f;
        float ps4 = 0.f, ps5 = 0.f, ps6 = 0.f, ps7 = 0.f;
        const int stmax = 2 * nchain;
#pragma unroll
        for (int st = 0; st < 8; ++st) {
            if (st < stmax) {
                float p0 = 0.f, p1 = 0.f, p2 = 0.f, p3 = 0.f;
                float p4 = 0.f, p5 = 0.f, p6 = 0.f, p7 = 0.f;
                if (st < nsub) {
                    p0 = __expf(sacc0[st][0] - mn0);
                    p1 = __expf(sacc0[st][1] - mn1);
                    p2 = __expf(sacc0[st][2] - mn2);
                    p3 = __expf(sacc0[st][3] - mn3);
                    p4 = __expf(sacc1[st][0] - mn4);
                    p5 = __expf(sacc1[st][1] - mn5);
                    p6 = __expf(sacc1[st][2] - mn6);
                    p7 = __expf(sacc1[st][3] - mn7);
                    ps0 += p0; ps1 += p1; ps2 += p2; ps3 += p3;
                    ps4 += p4; ps5 += p5; ps6 += p6; ps7 += p7;
                }
                const int col = st * 16 + n16;
                sPw[(quad * 4 + 0) * 136 + col] = f2bf(p0);
                sPw[(quad * 4 + 1) * 136 + col] = f2bf(p1);
                sPw[(quad * 4 + 2) * 136 + col] = f2bf(p2);
                sPw[(quad * 4 + 3) * 136 + col] = f2bf(p3);
                sPw[(16 + quad * 4 + 0) * 136 + col] = f2bf(p4);
                sPw[(16 + quad * 4 + 1) * 136 + col] = f2bf(p5);
                sPw[(16 + quad * 4 + 2) * 136 + col] = f2bf(p6);
                sPw[(16 + quad * 4 + 3) * 136 + col] = f2bf(p7);
            }
        }
        ps0 = dpp_sum16(ps0); ps1 = dpp_sum16(ps1);
        ps2 = dpp_sum16(ps2); ps3 = dpp_sum16(ps3);
        ps4 = dpp_sum16(ps4); ps5 = dpp_sum16(ps5);
        ps6 = dpp_sum16(ps6); ps7 = dpp_sum16(ps7);
        l0 = l0 * a0 + ps0; l1 = l1 * a1 + ps1;
        l2 = l2 * a2 + ps2; l3 = l3 * a3 + ps3;
        l4 = l4 * a4 + ps4; l5 = l5 * a5 + ps5;
        l6 = l6 * a6 + ps6; l7 = l7 * a7 + ps7;
#pragma unroll
        for (int nt = 0; nt < 4; ++nt) {
            oacc0[nt][0] *= a0; oacc0[nt][1] *= a1;
            oacc0[nt][2] *= a2; oacc0[nt][3] *= a3;
            oacc1[nt][0] *= a4; oacc1[nt][1] *= a5;
            oacc1[nt][2] *= a6; oacc1[nt][3] *= a7;
        }

        // ---- PV: both P tiles share each V fragment load ----
#pragma unroll
        for (int ch = 0; ch < 4; ++ch) {
            if (ch < nchain) {
                short8 pa0 = ld8(&sPw[n16 * 136 + ch * 32 + quad * 8]);
                short8 pa1 = ld8(&sPw[(16 + n16) * 136 + ch * 32 + quad * 8]);
                const size_t cbase =
                    (((size_t)(b * 64 + (kb >> 5) + ch)) * 4) << 9;
#pragma unroll
                for (int nt = 0; nt < 4; ++nt) {
                    short8 vv = ld8(Vf + cbase + (nt << 9) + lane * 8);
                    oacc0[nt] = MFMA(pa0, vv, oacc0[nt]);
                    oacc1[nt] = MFMA(pa1, vv, oacc1[nt]);
                }
            }
        }
    }

    // ---- flash-combine the 4 waves' partials (sO overlays sP) ----
#pragma unroll
    for (int nt = 0; nt < 4; ++nt)
#pragma unroll
        for (int r = 0; r < 4; ++r) {
            sOw[(quad * 4 + r) * 68 + nt * 16 + n16]      = oacc0[nt][r];
            sOw[(16 + quad * 4 + r) * 68 + nt * 16 + n16] = oacc1[nt][r];
        }
    if (n16 == 0) {
        sMl[w][quad * 4 + 0][0] = m0; sMl[w][quad * 4 + 0][1] = l0;
        sMl[w][quad * 4 + 1][0] = m1; sMl[w][quad * 4 + 1][1] = l1;
        sMl[w][quad * 4 + 2][0] = m2; sMl[w][quad * 4 + 2][1] = l2;
        sMl[w][quad * 4 + 3][0] = m3; sMl[w][quad * 4 + 3][1] = l3;
        sMl[w][16 + quad * 4 + 0][0] = m4; sMl[w][16 + quad * 4 + 0][1] = l4;
        sMl[w][16 + quad * 4 + 1][0] = m5; sMl[w][16 + quad * 4 + 1][1] = l5;
        sMl[w][16 + quad * 4 + 2][0] = m6; sMl[w][16 + quad * 4 + 2][1] = l6;
        sMl[w][16 + quad * 4 + 3][0] = m7; sMl[w][16 + quad * 4 + 3][1] = l7;
    }
    __syncthreads();

    // 256 threads: 32 rows x 64 cols, 8 floats (2x float4) per thread
    const int row  = t >> 3;
    const int col8 = (t & 7) * 8;
    float M = fmaxf(fmaxf(sMl[0][row][0], sMl[1][row][0]),
                    fmaxf(sMl[2][row][0], sMl[3][row][0]));
    float L = 0.f;
    float o0 = 0.f, o1 = 0.f, o2 = 0.f, o3 = 0.f;
    float o4 = 0.f, o5 = 0.f, o6 = 0.f, o7 = 0.f;
#pragma unroll
    for (int wv = 0; wv < 4; ++wv) {
        const float ew = __expf(sMl[wv][row][0] - M);
        L += ew * sMl[wv][row][1];
        const float* op = (const float*)scratch[wv] + row * 68 + col8;
        float4 va = *(const float4*)(op);
        float4 vb = *(const float4*)(op + 4);
        o0 += ew * va.x; o1 += ew * va.y; o2 += ew * va.z; o3 += ew * va.w;
        o4 += ew * vb.x; o5 += ew * vb.y; o6 += ew * vb.z; o7 += ew * vb.w;
    }
    const float inv = 1.0f / L;
    float* dst = O + ((size_t)(boff + q0 + row)) * DIM + col8;
    *(float4*)(dst)     = make_float4(o0 * inv, o1 * inv, o2 * inv, o3 * inv);
    *(float4*)(dst + 4) = make_float4(o4 * inv, o5 * inv, o6 * inv, o7 * inv);
}

extern "C" void kernel_launch(void* const* d_in, const int* in_sizes, int n_in,
                              void* d_out, int out_size, void* d_ws, size_t ws_size,
                              hipStream_t stream) {
    const float* q = (const float*)d_in[0];
    const float* k = (const float*)d_in[1];
    const float* v = (const float*)d_in[2];
    float* out = (float*)d_out;

    unsigned short* Kf = (unsigned short*)d_ws;   // 4 MB fragment-major hi/lo
    unsigned short* Vf = Kf + 2 * NEL;            // 2 MB fragment-major V

    prep<<<dim3(512 + 256), dim3(256), 0, stream>>>(k, v, Kf, Vf);
    attn_main<<<dim3(512), dim3(256), 0, stream>>>(q, Kf, Vf, out);
}

// Round 6
// 96.354 us; speedup vs baseline: 1.0267x; 1.0267x over previous
//
#include <hip/hip_runtime.h>

// Causal attention, fp32 in/out, B=8 S=2048 D=64, NO 1/sqrt(d) scaling.
// R21 = R20 (32-row q-tiles, halved K/V transactions) with the two
// implementation defects fixed:
//  - R20 post-mortem: traffic halved but attn ~28 -> ~37us. Cause theory:
//    (a) live state ~170 VGPR vs bare launch_bounds(256) heuristic cap
//        (likely 128) -> partial sacc SPILL to scratch (R16 precedent);
//    (b) per-subtile 4-loads-then-12-MFMAs killed the 8-in-flight MLP
//        that R18/R19 had.
//  - R21 fixes: __launch_bounds__(256, 1) -> allocator free up to 512
//    VGPR, no spills (occupancy ~2 waves/SIMD; proven irrelevant in
//    R17/R19). Paired subtile loads restored: 8 contiguous 1KB K-loads
//    in flight, then 24 MFMAs as 4 independent 6-chains.
//  - Math bit-identical to R20 (passed, absmax 0.03125): same chunk
//    partition (kb/128 mod 4, stride 512), same online-softmax order,
//    same 4-wave combine.
// Ledger: ~43us ws-poison fill + ~13us launch/misc fixed; K+V L2 traffic
// 203MB (floor ~6us); R18's lesson: the binding resource is TA/L1
// transaction issue, not bytes. Spill tripwire: attn WRITE_SIZE ~4MB.
// Fragment layouts (verified R2):
//   A[m][k]: m=lane&15, k=quad*8+j | B[k][n]: n=lane&15, k=quad*8+j
//   C/D:     col=lane&15, row=quad*4+reg
// Vf layout: chunk c(32 keys), dim-group nt: lane l holds
//   V[b][c*32+(l>>4)*8+j][nt*16+(l&15)], j=0..7 (16B, consecutive by lane).
// Kf layout: subtile S(16 keys), frag f: lane l holds 16B at
//   Kf + (b*128+S)*2048 + f*512 + l*8   (elements, 2B each)
//   f0/f1 = hi dims 0-31 / 32-63, f2/f3 = lo dims 0-31 / 32-63.

#define BATCH 8
#define SEQ 2048
#define DIM 64
#define NEL (BATCH * SEQ * DIM)

typedef __attribute__((ext_vector_type(8))) short short8;
typedef __attribute__((ext_vector_type(4))) float f32x4;

#define MFMA(a, b, c) __builtin_amdgcn_mfma_f32_16x16x32_bf16(a, b, c, 0, 0, 0)

__device__ __forceinline__ unsigned short f2bf(float x) {   // RNE
    unsigned u = __float_as_uint(x);
    unsigned r = u + 0x7fffu + ((u >> 16) & 1u);
    return (unsigned short)(r >> 16);
}
__device__ __forceinline__ float bf2f(unsigned short h) {
    return __uint_as_float(((unsigned)h) << 16);
}
__device__ __forceinline__ short8 ld8(const unsigned short* p) {
    return *(const short8*)p;
}
// truncation hi/lo split (R14-verified): hi = upper16(x); lo = trunc16(x-hi).
__device__ __forceinline__ void splitA(float4 a, float4 b, short8& h8, short8& l8) {
    float v[8] = {a.x, a.y, a.z, a.w, b.x, b.y, b.z, b.w};
#pragma unroll
    for (int i = 0; i < 8; ++i) {
        unsigned u  = __float_as_uint(v[i]);
        unsigned hu = u & 0xffff0000u;
        h8[i] = (short)(hu >> 16);
        float lf = v[i] - __uint_as_float(hu);
        l8[i] = (short)(__float_as_uint(lf) >> 16);
    }
}

__device__ __forceinline__ float dpp_max16(float x) {
    float o;
    o = __int_as_float(__builtin_amdgcn_update_dpp(0, __float_as_int(x), 0xB1, 0xF, 0xF, true));
    x = fmaxf(x, o);
    o = __int_as_float(__builtin_amdgcn_update_dpp(0, __float_as_int(x), 0x4E, 0xF, 0xF, true));
    x = fmaxf(x, o);
    o = __int_as_float(__builtin_amdgcn_update_dpp(0, __float_as_int(x), 0x141, 0xF, 0xF, true));
    x = fmaxf(x, o);
    o = __int_as_float(__builtin_amdgcn_update_dpp(0, __float_as_int(x), 0x140, 0xF, 0xF, true));
    return fmaxf(x, o);
}
__device__ __forceinline__ float dpp_sum16(float x) {
    float o;
    o = __int_as_float(__builtin_amdgcn_update_dpp(0, __float_as_int(x), 0xB1, 0xF, 0xF, true));
    x += o;
    o = __int_as_float(__builtin_amdgcn_update_dpp(0, __float_as_int(x), 0x4E, 0xF, 0xF, true));
    x += o;
    o = __int_as_float(__builtin_amdgcn_update_dpp(0, __float_as_int(x), 0x141, 0xF, 0xF, true));
    x += o;
    o = __int_as_float(__builtin_amdgcn_update_dpp(0, __float_as_int(x), 0x140, 0xF, 0xF, true));
    return x + o;
}

// ---- pre-pass: K fragment-major hi/lo (blk<512) + V fragment-major ----
__global__ __launch_bounds__(256) void prep(
    const float* __restrict__ K, const float* __restrict__ V,
    unsigned short* __restrict__ Kf, unsigned short* __restrict__ Vf)
{
    __shared__ unsigned short sT[64][72];   // [dim][key] for one 64-key tile
    const int blk = blockIdx.x;
    const int t = threadIdx.x;

    if (blk < 512) {
        // one thread = one (subtile, dim-half, lane) chunk: 8 fp32 -> hi8+lo8
        const int g  = blk * 256 + t;       // 0..131071
        const int l  = g & 63;
        const int h  = (g >> 6) & 1;
        const int Sg = g >> 7;              // b*128 + S, 0..1023
        const int b  = Sg >> 7;
        const int S  = Sg & 127;
        const int key = S * 16 + (l & 15);
        const float* src = K + ((size_t)(b * SEQ + key)) * DIM + h * 32 + (l >> 4) * 8;
        float4 a = *(const float4*)src;
        float4 c = *(const float4*)(src + 4);
        float v[8] = {a.x, a.y, a.z, a.w, c.x, c.y, c.z, c.w};
        short8 h8, l8;
#pragma unroll
        for (int i = 0; i < 8; ++i) {
            unsigned short hh = f2bf(v[i]);
            h8[i] = (short)hh;
            l8[i] = (short)f2bf(v[i] - bf2f(hh));
        }
        unsigned short* dst = Kf + (((size_t)Sg) << 11) + (h << 9) + l * 8;
        *(short8*)dst = h8;                  // frag f = h   (hi)
        *(short8*)(dst + 1024) = l8;         // frag f = 2+h (lo)
        return;
    }

    const int tile = blk - 512;             // 8 batches * 32 tiles of 64 keys
    const int b = tile >> 5;
    const int s0 = (tile & 31) * 64;
    const int srow = t >> 4;
    const int d4   = (t & 15) * 4;
#pragma unroll
    for (int i = 0; i < 4; ++i) {
        const int row = srow + i * 16;
        float4 v = *(const float4*)(V + ((size_t)(b * SEQ + s0 + row)) * DIM + d4);
        sT[d4 + 0][row] = f2bf(v.x);
        sT[d4 + 1][row] = f2bf(v.y);
        sT[d4 + 2][row] = f2bf(v.z);
        sT[d4 + 3][row] = f2bf(v.w);
    }
    __syncthreads();
#pragma unroll
    for (int i = 0; i < 2; ++i) {
        const int fid = t + i * 256;
        const int cc  = fid >> 8;
        const int nt  = (fid >> 6) & 3;
        const int l   = fid & 63;
        const int key = cc * 32 + (l >> 4) * 8;
        const int dim = nt * 16 + (l & 15);
        const int c   = (s0 >> 5) + cc;
        unsigned short* dst =
            Vf + ((((size_t)(b * 64 + c)) * 4 + nt) << 9) + l * 8;
        *(float4*)dst = *(const float4*)&sT[dim][key];
    }
}

// ---- main: 512 blocks x 256 threads (4 waves), 32 q-rows per block ----
__global__ __launch_bounds__(256, 1) void attn_main(
    const float* __restrict__ Q,
    const unsigned short* __restrict__ Kf,
    const unsigned short* __restrict__ Vf, float* __restrict__ O)
{
    // per-wave union scratch: sP (ushort[32][136]) == sO (float[32][68]) = 8704B
    __shared__ __align__(16) char scratch[4][8704];
    __shared__ float sMl[4][32][2];

    const int bid  = blockIdx.x;
    // snake over grid halves: CU c gets tiles {tl, 63-tl} -> const work
    const int gph  = bid >> 8;              // 0/1
    const int idx  = bid & 255;
    const int b    = idx & (BATCH - 1);
    const int tl   = idx >> 3;              // 0..31
    const int qt   = gph ? (63 - tl) : tl;  // 0..63

    const int t    = threadIdx.x;
    const int w    = t >> 6;
    const int lane = t & 63;
    const int quad = lane >> 4;
    const int n16  = lane & 15;
    const int boff = b * SEQ;

    unsigned short* sPw = (unsigned short*)scratch[w];   // [32][136]
    float*          sOw = (float*)scratch[w];            // [32][68]

    // base of this batch's Kf region, plus this lane's 16B slot
    const unsigned short* KfL = Kf + (((size_t)(b * 128)) << 11) + lane * 8;

    const int q0 = qt * 32;
    const int q_max = q0 + 31;

    // ---- Q fragments, both 16-row tiles: inline hi/lo truncation split ----
    short8 qAh0, qAl0, qAh1, qAl1, qBh0, qBl0, qBh1, qBl1;
    {
        const float* qa = Q + ((size_t)(boff + q0 + n16)) * DIM + quad * 8;
        splitA(*(const float4*)(qa),      *(const float4*)(qa + 4),  qAh0, qAl0);
        splitA(*(const float4*)(qa + 32), *(const float4*)(qa + 36), qAh1, qAl1);
        const float* qb = qa + 16 * DIM;
        splitA(*(const float4*)(qb),      *(const float4*)(qb + 4),  qBh0, qBl0);
        splitA(*(const float4*)(qb + 32), *(const float4*)(qb + 36), qBh1, qBl1);
    }

    float m0 = -1e30f, m1 = -1e30f, m2 = -1e30f, m3 = -1e30f;
    float m4 = -1e30f, m5 = -1e30f, m6 = -1e30f, m7 = -1e30f;
    float l0 = 0.f, l1 = 0.f, l2 = 0.f, l3 = 0.f;
    float l4 = 0.f, l5 = 0.f, l6 = 0.f, l7 = 0.f;
    f32x4 oacc0[4], oacc1[4];
#pragma unroll
    for (int i = 0; i < 4; ++i) {
        oacc0[i] = (f32x4){0.f, 0.f, 0.f, 0.f};
        oacc1[i] = (f32x4){0.f, 0.f, 0.f, 0.f};
    }

    for (int kb = w * 128; kb <= q_max; kb += 512) {
        const int nsub = min(8, ((q_max - kb) >> 4) + 1);
        const int nchain = (nsub + 1) >> 1;
        f32x4 sacc0[8], sacc1[8];

        // ---- QK^T: subtile pairs, 8 contiguous 1KB loads in flight,
        //      then 24 MFMAs as 4 independent 6-chains ----
#pragma unroll
        for (int gp = 0; gp < 4; ++gp) {
            const int stA = 2 * gp, stB = stA + 1;
            if (stA < nsub) {
                const unsigned short* pA = KfL + (((size_t)((kb >> 4) + stA)) << 11);
                short8 kA0 = ld8(pA),        kA1 = ld8(pA + 512);
                short8 kA2 = ld8(pA + 1024), kA3 = ld8(pA + 1536);
                const bool okB = (stB < nsub);
                const unsigned short* pB = KfL + (((size_t)((kb >> 4) + stB)) << 11);
                short8 kB0, kB1, kB2, kB3;
                if (okB) {
                    kB0 = ld8(pB);        kB1 = ld8(pB + 512);
                    kB2 = ld8(pB + 1024); kB3 = ld8(pB + 1536);
                }
                f32x4 aA = (f32x4){0.f, 0.f, 0.f, 0.f};
                f32x4 bA = (f32x4){0.f, 0.f, 0.f, 0.f};
                aA = MFMA(qAh0, kA0, aA);  bA = MFMA(qBh0, kA0, bA);
                aA = MFMA(qAh1, kA1, aA);  bA = MFMA(qBh1, kA1, bA);
                aA = MFMA(qAh0, kA2, aA);  bA = MFMA(qBh0, kA2, bA);
                aA = MFMA(qAh1, kA3, aA);  bA = MFMA(qBh1, kA3, bA);
                aA = MFMA(qAl0, kA0, aA);  bA = MFMA(qBl0, kA0, bA);
                aA = MFMA(qAl1, kA1, aA);  bA = MFMA(qBl1, kA1, bA);
                sacc0[stA] = aA; sacc1[stA] = bA;
                if (okB) {
                    f32x4 aB = (f32x4){0.f, 0.f, 0.f, 0.f};
                    f32x4 bB = (f32x4){0.f, 0.f, 0.f, 0.f};
                    aB = MFMA(qAh0, kB0, aB);  bB = MFMA(qBh0, kB0, bB);
                    aB = MFMA(qAh1, kB1, aB);  bB = MFMA(qBh1, kB1, bB);
                    aB = MFMA(qAh0, kB2, aB);  bB = MFMA(qBh0, kB2, bB);
                    aB = MFMA(qAh1, kB3, aB);  bB = MFMA(qBh1, kB3, bB);
                    aB = MFMA(qAl0, kB0, aB);  bB = MFMA(qBl0, kB0, bB);
                    aB = MFMA(qAl1, kB1, aB);  bB = MFMA(qBl1, kB1, bB);
                    sacc0[stB] = aB; sacc1[stB] = bB;
                } else {
                    sacc0[stB] = (f32x4){-1e30f, -1e30f, -1e30f, -1e30f};
                    sacc1[stB] = (f32x4){-1e30f, -1e30f, -1e30f, -1e30f};
                }
            } else {
                sacc0[stA] = (f32x4){-1e30f, -1e30f, -1e30f, -1e30f};
                sacc1[stA] = (f32x4){-1e30f, -1e30f, -1e30f, -1e30f};
                sacc0[stB] = (f32x4){-1e30f, -1e30f, -1e30f, -1e30f};
                sacc1[stB] = (f32x4){-1e30f, -1e30f, -1e30f, -1e30f};
            }
        }

        // ---- causal mask: chunk overlaps some query row ----
        if (kb + 127 > q0) {
#pragma unroll
            for (int st = 0; st < 8; ++st) {
                if (st < nsub) {
                    const int key = kb + st * 16 + n16;
#pragma unroll
                    for (int r = 0; r < 4; ++r) {
                        if (key > q0 + quad * 4 + r)      sacc0[st][r] = -1e30f;
                        if (key > q0 + 16 + quad * 4 + r) sacc1[st][r] = -1e30f;
                    }
                }
            }
        }

        // ---- online softmax over 128 keys x 32 rows (DPP reductions) ----
        float mt0 = sacc0[0][0], mt1 = sacc0[0][1], mt2 = sacc0[0][2], mt3 = sacc0[0][3];
        float mt4 = sacc1[0][0], mt5 = sacc1[0][1], mt6 = sacc1[0][2], mt7 = sacc1[0][3];
#pragma unroll
        for (int st = 1; st < 8; ++st) {
            mt0 = fmaxf(mt0, sacc0[st][0]);
            mt1 = fmaxf(mt1, sacc0[st][1]);
            mt2 = fmaxf(mt2, sacc0[st][2]);
            mt3 = fmaxf(mt3, sacc0[st][3]);
            mt4 = fmaxf(mt4, sacc1[st][0]);
            mt5 = fmaxf(mt5, sacc1[st][1]);
            mt6 = fmaxf(mt6, sacc1[st][2]);
            mt7 = fmaxf(mt7, sacc1[st][3]);
        }
        mt0 = dpp_max16(mt0); mt1 = dpp_max16(mt1);
        mt2 = dpp_max16(mt2); mt3 = dpp_max16(mt3);
        mt4 = dpp_max16(mt4); mt5 = dpp_max16(mt5);
        mt6 = dpp_max16(mt6); mt7 = dpp_max16(mt7);
        const float mn0 = fmaxf(m0, mt0), mn1 = fmaxf(m1, mt1);
        const float mn2 = fmaxf(m2, mt2), mn3 = fmaxf(m3, mt3);
        const float mn4 = fmaxf(m4, mt4), mn5 = fmaxf(m5, mt5);
        const float mn6 = fmaxf(m6, mt6), mn7 = fmaxf(m7, mt7);
        const float a0 = __expf(m0 - mn0), a1 = __expf(m1 - mn1);
        const float a2 = __expf(m2 - mn2), a3 = __expf(m3 - mn3);
        const float a4 = __expf(m4 - mn4), a5 = __expf(m5 - mn5);
        const float a6 = __expf(m6 - mn6), a7 = __expf(m7 - mn7);
        m0 = mn0; m1 = mn1; m2 = mn2; m3 = mn3;
        m4 = mn4; m5 = mn5; m6 = mn6; m7 = mn7;

        float ps0 = 0.f, ps1 = 0.f, ps2 = 0.f, ps3 = 0.f;
        float ps4 = 0.f, ps5 = 0.f, ps6 = 0.f, ps7 = 0.f;
        const int stmax = 2 * nchain;
#pragma unroll
        for (int st = 0; st < 8; ++st) {
            if (st < stmax) {
                float p0 = 0.f, p1 = 0.f, p2 = 0.f, p3 = 0.f;
                float p4 = 0.f, p5 = 0.f, p6 = 0.f, p7 = 0.f;
                if (st < nsub) {
                    p0 = __expf(sacc0[st][0] - mn0);
                    p1 = __expf(sacc0[st][1] - mn1);
                    p2 = __expf(sacc0[st][2] - mn2);
                    p3 = __expf(sacc0[st][3] - mn3);
                    p4 = __expf(sacc1[st][0] - mn4);
                    p5 = __expf(sacc1[st][1] - mn5);
                    p6 = __expf(sacc1[st][2] - mn6);
                    p7 = __expf(sacc1[st][3] - mn7);
                    ps0 += p0; ps1 += p1; ps2 += p2; ps3 += p3;
                    ps4 += p4; ps5 += p5; ps6 += p6; ps7 += p7;
                }
                const int col = st * 16 + n16;
                sPw[(quad * 4 + 0) * 136 + col] = f2bf(p0);
                sPw[(quad * 4 + 1) * 136 + col] = f2bf(p1);
                sPw[(quad * 4 + 2) * 136 + col] = f2bf(p2);
                sPw[(quad * 4 + 3) * 136 + col] = f2bf(p3);
                sPw[(16 + quad * 4 + 0) * 136 + col] = f2bf(p4);
                sPw[(16 + quad * 4 + 1) * 136 + col] = f2bf(p5);
                sPw[(16 + quad * 4 + 2) * 136 + col] = f2bf(p6);
                sPw[(16 + quad * 4 + 3) * 136 + col] = f2bf(p7);
            }
        }
        ps0 = dpp_sum16(ps0); ps1 = dpp_sum16(ps1);
        ps2 = dpp_sum16(ps2); ps3 = dpp_sum16(ps3);
        ps4 = dpp_sum16(ps4); ps5 = dpp_sum16(ps5);
        ps6 = dpp_sum16(ps6); ps7 = dpp_sum16(ps7);
        l0 = l0 * a0 + ps0; l1 = l1 * a1 + ps1;
        l2 = l2 * a2 + ps2; l3 = l3 * a3 + ps3;
        l4 = l4 * a4 + ps4; l5 = l5 * a5 + ps5;
        l6 = l6 * a6 + ps6; l7 = l7 * a7 + ps7;
#pragma unroll
        for (int nt = 0; nt < 4; ++nt) {
            oacc0[nt][0] *= a0; oacc0[nt][1] *= a1;
            oacc0[nt][2] *= a2; oacc0[nt][3] *= a3;
            oacc1[nt][0] *= a4; oacc1[nt][1] *= a5;
            oacc1[nt][2] *= a6; oacc1[nt][3] *= a7;
        }

        // ---- PV: both P tiles share each V fragment load ----
#pragma unroll
        for (int ch = 0; ch < 4; ++ch) {
            if (ch < nchain) {
                short8 pa0 = ld8(&sPw[n16 * 136 + ch * 32 + quad * 8]);
                short8 pa1 = ld8(&sPw[(16 + n16) * 136 + ch * 32 + quad * 8]);
                const size_t cbase =
                    (((size_t)(b * 64 + (kb >> 5) + ch)) * 4) << 9;
#pragma unroll
                for (int nt = 0; nt < 4; ++nt) {
                    short8 vv = ld8(Vf + cbase + (nt << 9) + lane * 8);
                    oacc0[nt] = MFMA(pa0, vv, oacc0[nt]);
                    oacc1[nt] = MFMA(pa1, vv, oacc1[nt]);
                }
            }
        }
    }

    // ---- flash-combine the 4 waves' partials (sO overlays sP) ----
#pragma unroll
    for (int nt = 0; nt < 4; ++nt)
#pragma unroll
        for (int r = 0; r < 4; ++r) {
            sOw[(quad * 4 + r) * 68 + nt * 16 + n16]      = oacc0[nt][r];
            sOw[(16 + quad * 4 + r) * 68 + nt * 16 + n16] = oacc1[nt][r];
        }
    if (n16 == 0) {
        sMl[w][quad * 4 + 0][0] = m0; sMl[w][quad * 4 + 0][1] = l0;
        sMl[w][quad * 4 + 1][0] = m1; sMl[w][quad * 4 + 1][1] = l1;
        sMl[w][quad * 4 + 2][0] = m2; sMl[w][quad * 4 + 2][1] = l2;
        sMl[w][quad * 4 + 3][0] = m3; sMl[w][quad * 4 + 3][1] = l3;
        sMl[w][16 + quad * 4 + 0][0] = m4; sMl[w][16 + quad * 4 + 0][1] = l4;
        sMl[w][16 + quad * 4 + 1][0] = m5; sMl[w][16 + quad * 4 + 1][1] = l5;
        sMl[w][16 + quad * 4 + 2][0] = m6; sMl[w][16 + quad * 4 + 2][1] = l6;
        sMl[w][16 + quad * 4 + 3][0] = m7; sMl[w][16 + quad * 4 + 3][1] = l7;
    }
    __syncthreads();

    // 256 threads: 32 rows x 64 cols, 8 floats (2x float4) per thread
    const int row  = t >> 3;
    const int col8 = (t & 7) * 8;
    float M = fmaxf(fmaxf(sMl[0][row][0], sMl[1][row][0]),
                    fmaxf(sMl[2][row][0], sMl[3][row][0]));
    float L = 0.f;
    float o0 = 0.f, o1 = 0.f, o2 = 0.f, o3 = 0.f;
    float o4 = 0.f, o5 = 0.f, o6 = 0.f, o7 = 0.f;
#pragma unroll
    for (int wv = 0; wv < 4; ++wv) {
        const float ew = __expf(sMl[wv][row][0] - M);
        L += ew * sMl[wv][row][1];
        const float* op = (const float*)scratch[wv] + row * 68 + col8;
        float4 va = *(const float4*)(op);
        float4 vb = *(const float4*)(op + 4);
        o0 += ew * va.x; o1 += ew * va.y; o2 += ew * va.z; o3 += ew * va.w;
        o4 += ew * vb.x; o5 += ew * vb.y; o6 += ew * vb.z; o7 += ew * vb.w;
    }
    const float inv = 1.0f / L;
    float* dst = O + ((size_t)(boff + q0 + row)) * DIM + col8;
    *(float4*)(dst)     = make_float4(o0 * inv, o1 * inv, o2 * inv, o3 * inv);
    *(float4*)(dst + 4) = make_float4(o4 * inv, o5 * inv, o6 * inv, o7 * inv);
}

extern "C" void kernel_launch(void* const* d_in, const int* in_sizes, int n_in,
                              void* d_out, int out_size, void* d_ws, size_t ws_size,
                              hipStream_t stream) {
    const float* q = (const float*)d_in[0];
    const float* k = (const float*)d_in[1];
    const float* v = (const float*)d_in[2];
    float* out = (float*)d_out;

    unsigned short* Kf = (unsigned short*)d_ws;   // 4 MB fragment-major hi/lo
    unsigned short* Vf = Kf + 2 * NEL;            // 2 MB fragment-major V

    prep<<<dim3(512 + 256), dim3(256), 0, stream>>>(k, v, Kf, Vf);
    attn_main<<<dim3(512), dim3(256), 0, stream>>>(q, Kf, Vf, out);
}

// Round 7
// 90.273 us; speedup vs baseline: 1.0958x; 1.0674x over previous
//
#include <hip/hip_runtime.h>

// Causal attention, fp32 in/out, B=8 S=2048 D=64, NO 1/sqrt(d) scaling.
// R22 = R19 (best: 90.27us total, attn ~28us) + packed P-conversion:
//  - R20/R21 post-mortem: 32-row tiles halved K/V loads, BOTH lost to R19
//    (98.9 / 96.4 vs 90.3) -> load count is NOT binding post-R18. Line dead.
//  - Standing regime: invariant to occupancy (R17/R19) and load volume
//    (R20/R21); only load-shape (R18) ever paid. Remaining candidate: the
//    ~280-op serial VALU softmax section per chunk (R15 counters: VALU:MFMA
//    busy 3.4:1). Largest piece: P->bf16 via manual RNE = 32 x ~4 int ops.
//  - R22: v_cvt_pk_bf16_f32 (1 inst packs 2 f32->2 bf16, RNE; no builtin
//    on gfx950, inline asm per T12) replaces each 8-op pair with cvt+shift:
//    ~96 fewer VALU ops/chunk on the QK->PV critical path. RNE==RNE ->
//    bit-identical; absmax must stay exactly 0.03125.
//  - Everything else byte-identical to R19. Pre-committed: if neutral,
//    VALU theory dies -> L2/L3 service path is the limit (test XCD-batch
//    locality or declare roofline).
// Ledger: ~42us ws-poison fill + ~6us prep + ~13us launch/misc fixed.
// Fragment layouts (verified R2):
//   A[m][k]: m=lane&15, k=quad*8+j | B[k][n]: n=lane&15, k=quad*8+j
//   C/D:     col=lane&15, row=quad*4+reg
// Vf layout: chunk c(32 keys), dim-group nt: lane l holds
//   V[b][c*32+(l>>4)*8+j][nt*16+(l&15)], j=0..7 (16B, consecutive by lane).
// Kf layout: subtile S(16 keys), frag f: lane l holds 16B at
//   Kf + (b*128+S)*2048 + f*512 + l*8   (elements, 2B each)
//   f0/f1 = hi dims 0-31 / 32-63, f2/f3 = lo dims 0-31 / 32-63.

#define BATCH 8
#define SEQ 2048
#define DIM 64
#define NEL (BATCH * SEQ * DIM)

typedef __attribute__((ext_vector_type(8))) short short8;
typedef __attribute__((ext_vector_type(4))) float f32x4;

#define MFMA(a, b, c) __builtin_amdgcn_mfma_f32_16x16x32_bf16(a, b, c, 0, 0, 0)

__device__ __forceinline__ unsigned short f2bf(float x) {   // RNE
    unsigned u = __float_as_uint(x);
    unsigned r = u + 0x7fffu + ((u >> 16) & 1u);
    return (unsigned short)(r >> 16);
}
__device__ __forceinline__ float bf2f(unsigned short h) {
    return __uint_as_float(((unsigned)h) << 16);
}
// packed f32x2 -> bf16x2, RNE; lo 16 bits from a, hi 16 bits from b.
__device__ __forceinline__ unsigned cvt_pk_bf16(float a, float b) {
    unsigned r;
    asm("v_cvt_pk_bf16_f32 %0, %1, %2" : "=v"(r) : "v"(a), "v"(b));
    return r;
}
__device__ __forceinline__ short8 ld8(const unsigned short* p) {
    return *(const short8*)p;
}
// truncation hi/lo split (R14-verified): hi = upper16(x); lo = trunc16(x-hi).
__device__ __forceinline__ void splitA(float4 a, float4 b, short8& h8, short8& l8) {
    float v[8] = {a.x, a.y, a.z, a.w, b.x, b.y, b.z, b.w};
#pragma unroll
    for (int i = 0; i < 8; ++i) {
        unsigned u  = __float_as_uint(v[i]);
        unsigned hu = u & 0xffff0000u;
        h8[i] = (short)(hu >> 16);
        float lf = v[i] - __uint_as_float(hu);
        l8[i] = (short)(__float_as_uint(lf) >> 16);
    }
}

__device__ __forceinline__ float dpp_max16(float x) {
    float o;
    o = __int_as_float(__builtin_amdgcn_update_dpp(0, __float_as_int(x), 0xB1, 0xF, 0xF, true));
    x = fmaxf(x, o);
    o = __int_as_float(__builtin_amdgcn_update_dpp(0, __float_as_int(x), 0x4E, 0xF, 0xF, true));
    x = fmaxf(x, o);
    o = __int_as_float(__builtin_amdgcn_update_dpp(0, __float_as_int(x), 0x141, 0xF, 0xF, true));
    x = fmaxf(x, o);
    o = __int_as_float(__builtin_amdgcn_update_dpp(0, __float_as_int(x), 0x140, 0xF, 0xF, true));
    return fmaxf(x, o);
}
__device__ __forceinline__ float dpp_sum16(float x) {
    float o;
    o = __int_as_float(__builtin_amdgcn_update_dpp(0, __float_as_int(x), 0xB1, 0xF, 0xF, true));
    x += o;
    o = __int_as_float(__builtin_amdgcn_update_dpp(0, __float_as_int(x), 0x4E, 0xF, 0xF, true));
    x += o;
    o = __int_as_float(__builtin_amdgcn_update_dpp(0, __float_as_int(x), 0x141, 0xF, 0xF, true));
    x += o;
    o = __int_as_float(__builtin_amdgcn_update_dpp(0, __float_as_int(x), 0x140, 0xF, 0xF, true));
    return x + o;
}

// ---- pre-pass: K fragment-major hi/lo (blk<512) + V fragment-major ----
__global__ __launch_bounds__(256) void prep(
    const float* __restrict__ K, const float* __restrict__ V,
    unsigned short* __restrict__ Kf, unsigned short* __restrict__ Vf)
{
    __shared__ unsigned short sT[64][72];   // [dim][key] for one 64-key tile
    const int blk = blockIdx.x;
    const int t = threadIdx.x;

    if (blk < 512) {
        // one thread = one (subtile, dim-half, lane) chunk: 8 fp32 -> hi8+lo8
        const int g  = blk * 256 + t;       // 0..131071
        const int l  = g & 63;
        const int h  = (g >> 6) & 1;
        const int Sg = g >> 7;              // b*128 + S, 0..1023
        const int b  = Sg >> 7;
        const int S  = Sg & 127;
        const int key = S * 16 + (l & 15);
        const float* src = K + ((size_t)(b * SEQ + key)) * DIM + h * 32 + (l >> 4) * 8;
        float4 a = *(const float4*)src;
        float4 c = *(const float4*)(src + 4);
        float v[8] = {a.x, a.y, a.z, a.w, c.x, c.y, c.z, c.w};
        short8 h8, l8;
#pragma unroll
        for (int i = 0; i < 8; ++i) {
            unsigned short hh = f2bf(v[i]);
            h8[i] = (short)hh;
            l8[i] = (short)f2bf(v[i] - bf2f(hh));
        }
        unsigned short* dst = Kf + (((size_t)Sg) << 11) + (h << 9) + l * 8;
        *(short8*)dst = h8;                  // frag f = h   (hi)
        *(short8*)(dst + 1024) = l8;         // frag f = 2+h (lo)
        return;
    }

    const int tile = blk - 512;             // 8 batches * 32 tiles of 64 keys
    const int b = tile >> 5;
    const int s0 = (tile & 31) * 64;
    const int srow = t >> 4;
    const int d4   = (t & 15) * 4;
#pragma unroll
    for (int i = 0; i < 4; ++i) {
        const int row = srow + i * 16;
        float4 v = *(const float4*)(V + ((size_t)(b * SEQ + s0 + row)) * DIM + d4);
        sT[d4 + 0][row] = f2bf(v.x);
        sT[d4 + 1][row] = f2bf(v.y);
        sT[d4 + 2][row] = f2bf(v.z);
        sT[d4 + 3][row] = f2bf(v.w);
    }
    __syncthreads();
#pragma unroll
    for (int i = 0; i < 2; ++i) {
        const int fid = t + i * 256;
        const int cc  = fid >> 8;
        const int nt  = (fid >> 6) & 3;
        const int l   = fid & 63;
        const int key = cc * 32 + (l >> 4) * 8;
        const int dim = nt * 16 + (l & 15);
        const int c   = (s0 >> 5) + cc;
        unsigned short* dst =
            Vf + ((((size_t)(b * 64 + c)) * 4 + nt) << 9) + l * 8;
        *(float4*)dst = *(const float4*)&sT[dim][key];
    }
}

// ---- main: 1024 blocks x 256 threads (4 waves), ONE q-tile per block ----
__global__ __launch_bounds__(256) void attn_main(
    const float* __restrict__ Q,
    const unsigned short* __restrict__ Kf,
    const unsigned short* __restrict__ Vf, float* __restrict__ O)
{
    // per-wave union scratch: sP (ushort[16][136]) == sO (float[16][68]) = 4352B
    __shared__ __align__(16) char scratch[4][4352];
    __shared__ float sMl[4][16][2];

    const int bid  = blockIdx.x;
    // snake mapping: per-CU work sum constant under striped assignment
    const int g    = bid >> 8;              // grid quarter 0..3
    const int idx  = bid & 255;
    const int b    = idx & (BATCH - 1);
    const int tl   = idx >> 3;              // 0..31
    const int qt   = (g & 1) ? (g * 32 + 31 - tl) : (g * 32 + tl);

    const int t    = threadIdx.x;
    const int w    = t >> 6;
    const int lane = t & 63;
    const int quad = lane >> 4;
    const int n16  = lane & 15;
    const int boff = b * SEQ;

    unsigned short* sPw = (unsigned short*)scratch[w];   // [16][136]
    float*          sOw = (float*)scratch[w];            // [16][68]

    // base of this batch's Kf region, plus this lane's 16B slot
    const unsigned short* KfL = Kf + (((size_t)(b * 128)) << 11) + lane * 8;

    const int q0 = qt * 16;
    const int q_max = q0 + 15;

    // ---- Q fragments: inline fp32 -> hi/lo truncation split ----
    short8 qh0, ql0, qh1, ql1;
    {
        const float* qb = Q + ((size_t)(boff + q0 + n16)) * DIM + quad * 8;
        splitA(*(const float4*)(qb),      *(const float4*)(qb + 4),  qh0, ql0);
        splitA(*(const float4*)(qb + 32), *(const float4*)(qb + 36), qh1, ql1);
    }

    float m0 = -1e30f, m1 = -1e30f, m2 = -1e30f, m3 = -1e30f;
    float l0 = 0.f, l1 = 0.f, l2 = 0.f, l3 = 0.f;
    f32x4 oacc[4];
#pragma unroll
    for (int i = 0; i < 4; ++i) oacc[i] = (f32x4){0.f, 0.f, 0.f, 0.f};

    for (int kb = w * 128; kb <= q_max; kb += 512) {
        const int rem  = q_max - kb;
        const int nsub = min(8, (rem >> 4) + 1);
        const int nchain = (nsub + 1) >> 1;
        f32x4 sacc[8];

        // ---- QK^T: 8 subtiles in pairs; contiguous 1KB frag loads ----
#pragma unroll
        for (int gp = 0; gp < 4; ++gp) {
            const int stA = 2 * gp, stB = stA + 1;
            if (stA < nsub) {
                const unsigned short* pA = KfL + (((size_t)((kb >> 4) + stA)) << 11);
                short8 khA0 = ld8(pA),        khA1 = ld8(pA + 512);
                short8 klA0 = ld8(pA + 1024), klA1 = ld8(pA + 1536);
                const bool okB = (stB < nsub);
                const unsigned short* pB = KfL + (((size_t)((kb >> 4) + stB)) << 11);
                short8 khB0, khB1, klB0, klB1;
                if (okB) {
                    khB0 = ld8(pB);        khB1 = ld8(pB + 512);
                    klB0 = ld8(pB + 1024); klB1 = ld8(pB + 1536);
                }
                f32x4 accA = (f32x4){0.f, 0.f, 0.f, 0.f};
                accA = MFMA(qh0, khA0, accA);
                accA = MFMA(qh1, khA1, accA);
                accA = MFMA(qh0, klA0, accA);
                accA = MFMA(qh1, klA1, accA);
                accA = MFMA(ql0, khA0, accA);
                accA = MFMA(ql1, khA1, accA);
                sacc[stA] = accA;
                if (okB) {
                    f32x4 accB = (f32x4){0.f, 0.f, 0.f, 0.f};
                    accB = MFMA(qh0, khB0, accB);
                    accB = MFMA(qh1, khB1, accB);
                    accB = MFMA(qh0, klB0, accB);
                    accB = MFMA(qh1, klB1, accB);
                    accB = MFMA(ql0, khB0, accB);
                    accB = MFMA(ql1, khB1, accB);
                    sacc[stB] = accB;
                } else {
                    sacc[stB] = (f32x4){-1e30f, -1e30f, -1e30f, -1e30f};
                }
            } else {
                sacc[stA] = (f32x4){-1e30f, -1e30f, -1e30f, -1e30f};
                sacc[stB] = (f32x4){-1e30f, -1e30f, -1e30f, -1e30f};
            }
        }

        // ---- causal mask: any chunk overlapping any query row ----
        if (kb + 127 > q0) {
#pragma unroll
            for (int st = 0; st < 8; ++st) {
                if (st < nsub) {
                    const int key = kb + st * 16 + n16;
#pragma unroll
                    for (int r = 0; r < 4; ++r)
                        if (key > q0 + quad * 4 + r) sacc[st][r] = -1e30f;
                }
            }
        }

        // ---- online softmax over 128 keys (DPP reductions) ----
        float mt0 = sacc[0][0], mt1 = sacc[0][1], mt2 = sacc[0][2], mt3 = sacc[0][3];
#pragma unroll
        for (int st = 1; st < 8; ++st) {
            mt0 = fmaxf(mt0, sacc[st][0]);
            mt1 = fmaxf(mt1, sacc[st][1]);
            mt2 = fmaxf(mt2, sacc[st][2]);
            mt3 = fmaxf(mt3, sacc[st][3]);
        }
        mt0 = dpp_max16(mt0); mt1 = dpp_max16(mt1);
        mt2 = dpp_max16(mt2); mt3 = dpp_max16(mt3);
        const float mn0 = fmaxf(m0, mt0), mn1 = fmaxf(m1, mt1);
        const float mn2 = fmaxf(m2, mt2), mn3 = fmaxf(m3, mt3);
        const float a0 = __expf(m0 - mn0), a1 = __expf(m1 - mn1);
        const float a2 = __expf(m2 - mn2), a3 = __expf(m3 - mn3);
        m0 = mn0; m1 = mn1; m2 = mn2; m3 = mn3;

        float ps0 = 0.f, ps1 = 0.f, ps2 = 0.f, ps3 = 0.f;
        const int stmax = 2 * nchain;
#pragma unroll
        for (int st = 0; st < 8; ++st) {
            if (st < stmax) {
                float p0 = 0.f, p1 = 0.f, p2 = 0.f, p3 = 0.f;
                if (st < nsub) {
                    p0 = __expf(sacc[st][0] - mn0);
                    p1 = __expf(sacc[st][1] - mn1);
                    p2 = __expf(sacc[st][2] - mn2);
                    p3 = __expf(sacc[st][3] - mn3);
                    ps0 += p0; ps1 += p1; ps2 += p2; ps3 += p3;
                }
                const int col = st * 16 + n16;
                // packed RNE convert: 2 cvt_pk + 2 shifts replace 4x ~4-op f2bf
                const unsigned r01 = cvt_pk_bf16(p0, p1);
                const unsigned r23 = cvt_pk_bf16(p2, p3);
                sPw[(quad * 4 + 0) * 136 + col] = (unsigned short)r01;
                sPw[(quad * 4 + 1) * 136 + col] = (unsigned short)(r01 >> 16);
                sPw[(quad * 4 + 2) * 136 + col] = (unsigned short)r23;
                sPw[(quad * 4 + 3) * 136 + col] = (unsigned short)(r23 >> 16);
            }
        }
        ps0 = dpp_sum16(ps0); ps1 = dpp_sum16(ps1);
        ps2 = dpp_sum16(ps2); ps3 = dpp_sum16(ps3);
        l0 = l0 * a0 + ps0; l1 = l1 * a1 + ps1;
        l2 = l2 * a2 + ps2; l3 = l3 * a3 + ps3;
#pragma unroll
        for (int nt = 0; nt < 4; ++nt) {
            oacc[nt][0] *= a0; oacc[nt][1] *= a1;
            oacc[nt][2] *= a2; oacc[nt][3] *= a3;
        }

        // ---- PV: P from same-wave LDS; V via dense fragment-major loads ----
#pragma unroll
        for (int ch = 0; ch < 4; ++ch) {
            if (ch < nchain) {
                short8 pa = ld8(&sPw[n16 * 136 + ch * 32 + quad * 8]);
                const size_t cbase =
                    (((size_t)(b * 64 + (kb >> 5) + ch)) * 4) << 9;
#pragma unroll
                for (int nt = 0; nt < 4; ++nt) {
                    short8 vv = ld8(Vf + cbase + (nt << 9) + lane * 8);
                    oacc[nt] = MFMA(pa, vv, oacc[nt]);
                }
            }
        }
    }

    // ---- flash-combine the 4 waves' partials (sO overlays sP) ----
#pragma unroll
    for (int nt = 0; nt < 4; ++nt)
#pragma unroll
        for (int r = 0; r < 4; ++r)
            sOw[(quad * 4 + r) * 68 + nt * 16 + n16] = oacc[nt][r];
    if (n16 == 0) {
        sMl[w][quad * 4 + 0][0] = m0; sMl[w][quad * 4 + 0][1] = l0;
        sMl[w][quad * 4 + 1][0] = m1; sMl[w][quad * 4 + 1][1] = l1;
        sMl[w][quad * 4 + 2][0] = m2; sMl[w][quad * 4 + 2][1] = l2;
        sMl[w][quad * 4 + 3][0] = m3; sMl[w][quad * 4 + 3][1] = l3;
    }
    __syncthreads();

    const int row  = t >> 4;
    const int col4 = (t & 15) * 4;
    float M = fmaxf(fmaxf(sMl[0][row][0], sMl[1][row][0]),
                    fmaxf(sMl[2][row][0], sMl[3][row][0]));
    float L = 0.f;
    float ox = 0.f, oy = 0.f, oz = 0.f, ow = 0.f;
#pragma unroll
    for (int wv = 0; wv < 4; ++wv) {
        const float ew = __expf(sMl[wv][row][0] - M);
        L += ew * sMl[wv][row][1];
        const float* op = (const float*)scratch[wv] + row * 68 + col4;
        ox += ew * op[0]; oy += ew * op[1]; oz += ew * op[2]; ow += ew * op[3];
    }
    const float inv = 1.0f / L;
    float4 res = make_float4(ox * inv, oy * inv, oz * inv, ow * inv);
    *(float4*)(O + ((size_t)(boff + q0 + row)) * DIM + col4) = res;
}

extern "C" void kernel_launch(void* const* d_in, const int* in_sizes, int n_in,
                              void* d_out, int out_size, void* d_ws, size_t ws_size,
                              hipStream_t stream) {
    const float* q = (const float*)d_in[0];
    const float* k = (const float*)d_in[1];
    const float* v = (const float*)d_in[2];
    float* out = (float*)d_out;

    unsigned short* Kf = (unsigned short*)d_ws;   // 4 MB fragment-major hi/lo
    unsigned short* Vf = Kf + 2 * NEL;            // 2 MB fragment-major V

    prep<<<dim3(512 + 256), dim3(256), 0, stream>>>(k, v, Kf, Vf);
    attn_main<<<dim3(1024), dim3(256), 0, stream>>>(q, Kf, Vf, out);
}